// Round 3
// baseline (450.675 us; speedup 1.0000x reference)
//
#include <hip/hip_runtime.h>

// MultiheadFeedForward: x[4,4096,2048] fp32; per-head FFN (H=16, dh=128, ff=512)
//   h = relu(x_h @ W1[h] + b1[h]);  out_h = h @ W2[h] + b2[h]
// R7: per-CU weight residency. R6 post-mortem: still latency-bound (all pipes
// <20%) with per-chunk L3-latency weight staging gated by vmcnt+12 barriers per
// block, weights staged 8x per CU (512 MB L2/L3 traffic). Fix: grid (16 strips
// x 16 heads) = 256 blocks = 1/CU; each block owns 1024 tokens and stages the
// FULL pre-swizzled W1 image (128 KB) into LDS ONCE via global_load_lds, then
// loops 8 m-tiles x 4 ff-chunks with ZERO in-loop staging. W2 fragments are
// plain register loads from L2 (plain-transposed w2t), all 16 issued at chunk
// top, consumed after GEMM1+barrier (~700 cyc cover, T14 pattern). 2 barriers
// per chunk (Hs WAR + Hs visibility); only manual wait is lgkmcnt(0).
// LDS = W1s 128K + Hs 32K = 160 KB exactly; 512 thr, 1 block/CU, 2 waves/SIMD.

typedef __attribute__((ext_vector_type(8))) short short8;
typedef __attribute__((ext_vector_type(4))) short short4v;
typedef __attribute__((ext_vector_type(4))) float f32x4;

#define NHEADS 16
#define DHEAD  128
#define NFF    512
#define DMODEL 2048
#define NTOK   16384
#define MT     128    // token tile
#define MTILES 8      // m-tiles per block (1024 tokens/block)
#define FC     128    // ff chunk
#define CH_SH  16384  // shorts per 128x128 chunk image (32 KB)

__device__ __forceinline__ short f2bf(float f) {
    unsigned u = __builtin_bit_cast(unsigned, f);
    u += 0x7FFFu + ((u >> 16) & 1u);   // RNE
    return (short)(u >> 16);
}

// async global->LDS, 16B per lane; LDS dest is wave-uniform base (+lane*16 by HW)
#define GLDS16(g, l) __builtin_amdgcn_global_load_lds( \
    (__attribute__((address_space(1))) void*)(g), \
    (__attribute__((address_space(3))) void*)(l), 16, 0, 0)

// Weight prep.
// which=0: W1[h] src [d=128][f=512] -> w1x[h][c][f_local][d-swizzled] (XOR
//          granule swizzle keyed by f&7) — staged linearly by ffn_main, read
//          with the same XOR (both-sides rule).
// which=1: W2[h] src [f=512][d=128] -> PLAIN w2t[h][d][f] bf16 (register-load
//          path needs no swizzle).
__global__ __launch_bounds__(256) void transpose_both(
        const float* __restrict__ W1, const float* __restrict__ W2,
        short* __restrict__ w1x, short* __restrict__ w2t) {
    __shared__ float tile[64][65];
    const int z = blockIdx.z;
    const int which = z & 1, h = z >> 1;
    const int C = which ? DHEAD : NFF;      // src cols
    const float* s = (which ? W2 : W1) + (size_t)h * DHEAD * NFF;
    short* dst = (which ? w2t : w1x) + (size_t)h * 4 * CH_SH;
    const int ct = C / 64;
    const int t0 = blockIdx.x;              // 0..15
    const int r0 = (t0 / ct) * 64, c0 = (t0 % ct) * 64;
    const int t = threadIdx.x;
    #pragma unroll
    for (int p = 0; p < 4; ++p) {
        int idx = p * 256 + t;
        int row = idx >> 4, col = (idx & 15) * 4;
        *(f32x4*)&tile[row][col] = *(const f32x4*)&s[(size_t)(r0 + row) * C + c0 + col];
    }
    __syncthreads();
    #pragma unroll
    for (int it = 0; it < 2; ++it) {
        int u = it * 256 + t;
        int dr = u >> 3, g = u & 7;         // dst row offset, src-row granule
        short8 v;
        #pragma unroll
        for (int j = 0; j < 8; ++j) v[j] = f2bf(tile[g * 8 + j][dr]);
        if (which == 0) {                   // dst row = f = c0+dr; col = d (swizzled)
            int f = c0 + dr;
            int gd = (r0 >> 3) + g;
            size_t idx = (size_t)(f >> 7) * CH_SH + (size_t)(f & 127) * 128 +
                         ((gd ^ (f & 7)) << 3);
            *(short8*)&dst[idx] = v;
        } else {                            // plain: dst row = d = c0+dr; col = f
            int d = c0 + dr;
            size_t idx = (size_t)d * NFF + r0 + g * 8;
            *(short8*)&dst[idx] = v;
        }
    }
}

// Grid (16 strips, 16 heads) = 256 blocks, block 512 (8 waves).
// GEMM1: D1[f][m] = W1T(A) x X(B); GEMM2: D2[d][m] = W2T(A) x H(B).
// A-frag: lane holds A[m'=l16][k=quad*8+j]; B-frag: B[k=quad*8+j][n=l16];
// C/D: col=l16, row=quad*4+reg. W1s/Hs reads use the XOR granule swizzle.
__global__ __launch_bounds__(512, 2) void ffn_main(
        const float* __restrict__ x,    // [NTOK][DMODEL] fp32
        const short* __restrict__ w1x,  // [H][4][CH_SH] swizzled bf16
        const float* __restrict__ b1,   // [H][NFF] fp32
        const short* __restrict__ w2t,  // [H][DHEAD][NFF] plain bf16
        const float* __restrict__ b2,   // [H][DHEAD] fp32
        float* __restrict__ out) {      // [NTOK][DMODEL] fp32
    __shared__ short W1s[4 * CH_SH];   // 128 KB: all 4 chunks, resident all block
    __shared__ short Hs[CH_SH];        // 32 KB hidden tile [m][f_local] swizzled

    const int h      = blockIdx.y;
    const int m_base = blockIdx.x * (MT * MTILES);
    const int tid  = threadIdx.x;
    const int lane = tid & 63;
    const int wave = tid >> 6;   // 0..7
    const int quad = lane >> 4;
    const int l16  = lane & 15;
    const int wf   = wave >> 2;  // f/d half (0/1)
    const int wm   = wave & 3;   // m quarter (0..3), 32 rows each
    const int s7   = l16 & 7;

    // ---- stage the ENTIRE W1 image once (128 KB, 16 x 1KB glds per wave)
    {
        const char* src = (const char*)(w1x + (size_t)h * 4 * CH_SH);
        char* dl = (char*)W1s;
        #pragma unroll
        for (int i = 0; i < 16; ++i)
            GLDS16(src + (wave * 16 + i) * 1024 + lane * 16,
                   dl + (wave * 16 + i) * 1024);
    }

    // hoisted b2 (constant per block)
    f32x4 bb2[4];
    #pragma unroll
    for (int di = 0; di < 4; ++di)
        bb2[di] = *(const f32x4*)(b2 + h * DHEAD + wf * 64 + di * 16 + quad * 4);

    const int arow = wf * 64 + l16;   // weight A-frag row base (+fi/di*16)
    const short* w2b = w2t + (size_t)h * DHEAD * NFF + (size_t)(wf * 64 + l16) * NFF + quad * 8;

    // one-time drain: W1s staged (+ bb2 landed)
    asm volatile("s_waitcnt vmcnt(0)" ::: "memory");
    __builtin_amdgcn_s_barrier();

    for (int mt = 0; mt < MTILES; ++mt) {
        const int m0 = m_base + mt * MT;

        // X as GEMM1 B-operand, kept bf16 in regs (32 VGPR)
        short8 xf[2][4];  // [mi][kk]
        {
            const float* xb = x + (size_t)(m0 + wm * 32) * DMODEL + h * DHEAD;
            #pragma unroll
            for (int mi = 0; mi < 2; ++mi)
                #pragma unroll
                for (int kk = 0; kk < 4; ++kk) {
                    const float* p = xb + (size_t)(mi * 16 + l16) * DMODEL + kk * 32 + quad * 8;
                    f32x4 a = *(const f32x4*)(p);
                    f32x4 b = *(const f32x4*)(p + 4);
                    short8 v;
                    v[0] = f2bf(a[0]); v[1] = f2bf(a[1]); v[2] = f2bf(a[2]); v[3] = f2bf(a[3]);
                    v[4] = f2bf(b[0]); v[5] = f2bf(b[1]); v[6] = f2bf(b[2]); v[7] = f2bf(b[3]);
                    xf[mi][kk] = v;
                }
        }

        f32x4 acc2[4][2];  // [di][mi], persistent across chunks
        #pragma unroll
        for (int di = 0; di < 4; ++di)
            #pragma unroll
            for (int mi = 0; mi < 2; ++mi)
                acc2[di][mi] = (f32x4){0.f, 0.f, 0.f, 0.f};

        #pragma unroll
        for (int c = 0; c < 4; ++c) {
            // ---- issue ALL W2 frags + bias for this chunk (regs; consumed
            // after GEMM1 + barrier => ~700 cyc latency cover, no manual waits)
            short8 wfr[4][4];  // [kk][di]
            #pragma unroll
            for (int kk = 0; kk < 4; ++kk)
                #pragma unroll
                for (int di = 0; di < 4; ++di)
                    wfr[kk][di] = *(const short8*)(w2b + (size_t)(di * 16) * NFF + c * FC + kk * 32);
            f32x4 bb1[4];
            #pragma unroll
            for (int fi = 0; fi < 4; ++fi)
                bb1[fi] = *(const f32x4*)(b1 + h * NFF + c * FC + wf * 64 + fi * 16 + quad * 4);

            // ---- GEMM1 from resident W1s + xf regs (no barrier needed before)
            f32x4 acc1[4][2];
            #pragma unroll
            for (int fi = 0; fi < 4; ++fi)
                #pragma unroll
                for (int mi = 0; mi < 2; ++mi)
                    acc1[fi][mi] = (f32x4){0.f, 0.f, 0.f, 0.f};
            #pragma unroll
            for (int kk = 0; kk < 4; ++kk) {
                short8 af[4];
                #pragma unroll
                for (int fi = 0; fi < 4; ++fi)
                    af[fi] = *(const short8*)&W1s[c * CH_SH + (arow + fi * 16) * 128 +
                                                 ((((kk << 2) + quad) ^ s7) << 3)];
                #pragma unroll
                for (int fi = 0; fi < 4; ++fi)
                    #pragma unroll
                    for (int mi = 0; mi < 2; ++mi)
                        acc1[fi][mi] = __builtin_amdgcn_mfma_f32_16x16x32_bf16(
                            af[fi], xf[mi][kk], acc1[fi][mi], 0, 0, 0);
            }

            // barrier A: all waves' previous-chunk GEMM2 reads of Hs are done
            // (each wave's GEMM1 above follows its own prev GEMM2 in program
            // order; GEMM1 touches only W1s) -> safe to overwrite Hs.
            __builtin_amdgcn_s_barrier();

            // ---- bias + relu -> Hs (swizzled 8B writes)
            #pragma unroll
            for (int fi = 0; fi < 4; ++fi) {
                #pragma unroll
                for (int mi = 0; mi < 2; ++mi) {
                    int mr = wm * 32 + mi * 16 + l16;
                    short4v hv;
                    #pragma unroll
                    for (int r = 0; r < 4; ++r)
                        hv[r] = f2bf(fmaxf(acc1[fi][mi][r] + bb1[fi][r], 0.f));
                    int g = (wf * 8 + fi * 2 + (quad >> 1)) ^ s7;
                    *(short4v*)&Hs[(size_t)mr * 128 + g * 8 + (quad & 1) * 4] = hv;
                }
            }
            // barrier B: Hs writes complete + visible before any wave reads
            asm volatile("s_waitcnt lgkmcnt(0)" ::: "memory");
            __builtin_amdgcn_s_barrier();

            // ---- GEMM2 from wfr regs + Hs
            #pragma unroll
            for (int kk = 0; kk < 4; ++kk) {
                short8 hfr[2];
                #pragma unroll
                for (int mi = 0; mi < 2; ++mi)
                    hfr[mi] = *(const short8*)&Hs[(size_t)(wm * 32 + mi * 16 + l16) * 128 +
                                                 ((((kk << 2) + quad) ^ s7) << 3)];
                #pragma unroll
                for (int di = 0; di < 4; ++di)
                    #pragma unroll
                    for (int mi = 0; mi < 2; ++mi)
                        acc2[di][mi] = __builtin_amdgcn_mfma_f32_16x16x32_bf16(
                            wfr[kk][di], hfr[mi], acc2[di][mi], 0, 0, 0);
            }
            // no trailing barrier: next chunk's barrier A protects Hs
        }

        // ---- epilogue: out[m][h*128+d] fp32, 16B stores (4 lanes/64B line)
        #pragma unroll
        for (int di = 0; di < 4; ++di) {
            #pragma unroll
            for (int mi = 0; mi < 2; ++mi) {
                int m = m0 + wm * 32 + mi * 16 + l16;
                f32x4 ov;
                #pragma unroll
                for (int r = 0; r < 4; ++r)
                    ov[r] = acc2[di][mi][r] + bb2[di][r];
                *(f32x4*)(out + (size_t)m * DMODEL + h * DHEAD + wf * 64 + di * 16 + quad * 4) = ov;
            }
        }
    }
}

extern "C" void kernel_launch(void* const* d_in, const int* in_sizes, int n_in,
                              void* d_out, int out_size, void* d_ws, size_t ws_size,
                              hipStream_t stream) {
    const float* x  = (const float*)d_in[0];
    const float* W1 = (const float*)d_in[1];
    const float* b1 = (const float*)d_in[2];
    const float* W2 = (const float*)d_in[3];
    const float* b2 = (const float*)d_in[4];
    float* out = (float*)d_out;

    short* w1x = (short*)d_ws;                                     // [16][4][CH_SH] swizzled
    short* w2t = (short*)d_ws + (size_t)NHEADS * 4 * CH_SH;        // [16][128][512] plain

    transpose_both<<<dim3(16, 1, 2 * NHEADS), 256, 0, stream>>>(W1, W2, w1x, w2t);
    ffn_main<<<dim3(NTOK / (MT * MTILES), NHEADS), 512, 0, stream>>>(x, w1x, b1, w2t, b2, out);
}

// Round 4
// 332.847 us; speedup vs baseline: 1.3540x; 1.3540x over previous
//
#include <hip/hip_runtime.h>

// MultiheadFeedForward: x[4,4096,2048] fp32; per-head FFN (H=16, dh=128, ff=512)
//   h = relu(x_h @ W1[h] + b1[h]);  out_h = h @ W2[h] + b2[h]
// R8 = R6 skeleton (best measured, 184us) minus its two measured stalls.
// R7 post-mortem: W2-from-global regressed (FETCH +260MB) — blocks round-robin
// over XCDs => every XCD L2 needs all 16 heads' W2 while x streaming evicts it.
// R8 fixes:
//  (1) BOTH W1 and W2 double-buffered in LDS, staged one chunk ahead via
//      global_load_lds; the only in-loop wait is vmcnt(0) over exactly the 8
//      prefetch glds, issued ~a full GEMM2 earlier. 2 barriers/chunk.
//  (2) 1-D grid id = mtile*16 + head => id%8 = head%8: all blocks of a head
//      pin to one XCD; its L2 holds just 2 heads' images (512 KB) hot, so
//      staging drains at L2 latency, fully covered.
//  (3) b1 via per-chunk register loads (frees LDS; 160 KB exactly).
// LDS: W1s[2]32K + W2s[2]32K + Hs 32K = 160 KB, 1 block/CU, 512 thr (8 waves).

typedef __attribute__((ext_vector_type(8))) short short8;
typedef __attribute__((ext_vector_type(4))) short short4v;
typedef __attribute__((ext_vector_type(4))) float f32x4;

#define NHEADS 16
#define DHEAD  128
#define NFF    512
#define DMODEL 2048
#define NTOK   16384
#define MT     128    // token tile per block
#define FC     128    // ff chunk
#define CH_SH  16384  // shorts per 128x128 chunk image (32 KB)

__device__ __forceinline__ short f2bf(float f) {
    unsigned u = __builtin_bit_cast(unsigned, f);
    u += 0x7FFFu + ((u >> 16) & 1u);   // RNE
    return (short)(u >> 16);
}

// async global->LDS, 16B per lane; LDS dest is wave-uniform base (+lane*16 by HW)
#define GLDS16(g, l) __builtin_amdgcn_global_load_lds( \
    (__attribute__((address_space(1))) void*)(g), \
    (__attribute__((address_space(3))) void*)(l), 16, 0, 0)

// Weight prep: fp32 -> bf16, transpose, write PRE-SWIZZLED 128x128 chunk
// images (XOR granule swizzle keyed by dest-row&7; staged linearly by
// ffn_main, read back with the same XOR — both-sides rule).
// which=0: W1[h] src [d=128][f=512] -> w1x[h][c][f_local][d-swz]
// which=1: W2[h] src [f=512][d=128] -> w2x[h][c][d][f_local-swz]
__global__ __launch_bounds__(256) void transpose_both(
        const float* __restrict__ W1, const float* __restrict__ W2,
        short* __restrict__ w1x, short* __restrict__ w2x) {
    __shared__ float tile[64][65];
    const int z = blockIdx.z;
    const int which = z & 1, h = z >> 1;
    const int C = which ? DHEAD : NFF;      // src cols
    const float* s = (which ? W2 : W1) + (size_t)h * DHEAD * NFF;
    short* dst = (which ? w2x : w1x) + (size_t)h * 4 * CH_SH;
    const int ct = C / 64;
    const int t0 = blockIdx.x;              // 0..15
    const int r0 = (t0 / ct) * 64, c0 = (t0 % ct) * 64;
    const int t = threadIdx.x;
    #pragma unroll
    for (int p = 0; p < 4; ++p) {
        int idx = p * 256 + t;
        int row = idx >> 4, col = (idx & 15) * 4;
        *(f32x4*)&tile[row][col] = *(const f32x4*)&s[(size_t)(r0 + row) * C + c0 + col];
    }
    __syncthreads();
    #pragma unroll
    for (int it = 0; it < 2; ++it) {
        int u = it * 256 + t;
        int dr = u >> 3, g = u & 7;         // dst row offset, src-row granule
        short8 v;
        #pragma unroll
        for (int j = 0; j < 8; ++j) v[j] = f2bf(tile[g * 8 + j][dr]);
        size_t idx;
        if (which == 0) {                   // dst row = f = c0+dr; col = d
            int f = c0 + dr;
            int gd = (r0 >> 3) + g;
            idx = (size_t)(f >> 7) * CH_SH + (size_t)(f & 127) * 128 + ((gd ^ (f & 7)) << 3);
        } else {                            // dst row = d = c0+dr; col = f_local
            int d = c0 + dr;
            int gf = ((r0 & 127) >> 3) + g;
            idx = (size_t)(r0 >> 7) * CH_SH + (size_t)d * 128 + ((gf ^ (d & 7)) << 3);
        }
        *(short8*)&dst[idx] = v;
    }
}

// Grid: 2048 blocks 1-D, id = mtile*16 + head (head-major XCD pinning).
// Block 512 (8 waves: wf = f/d half, wm = m quarter).
// GEMM1: D1[f][m] = W1T(A) x X(B); GEMM2: D2[d][m] = W2T(A) x H(B).
// A-frag: lane holds A[m'=l16][k=quad*8+j]; B-frag: B[k=quad*8+j][n=l16];
// C/D: col=l16, row=quad*4+reg. All LDS frag reads use the XOR granule swizzle.
__global__ __launch_bounds__(512, 2) void ffn_main(
        const float* __restrict__ x,    // [NTOK][DMODEL] fp32
        const short* __restrict__ w1x,  // [H][4][CH_SH] swizzled bf16
        const float* __restrict__ b1,   // [H][NFF] fp32
        const short* __restrict__ w2x,  // [H][4][CH_SH] swizzled bf16
        const float* __restrict__ b2,   // [H][DHEAD] fp32
        float* __restrict__ out) {      // [NTOK][DMODEL] fp32
    __shared__ short W1s[2][CH_SH];    // 64 KB double-buffered W1 chunk
    __shared__ short W2s[2][CH_SH];    // 64 KB double-buffered W2 chunk
    __shared__ short Hs[CH_SH];        // 32 KB hidden tile [m][f_local] swizzled

    const int id   = blockIdx.x;
    const int h    = id & 15;          // id%8 = head%8 -> head-pinned XCD
    const int m0   = (id >> 4) * MT;
    const int tid  = threadIdx.x;
    const int lane = tid & 63;
    const int wave = tid >> 6;   // 0..7
    const int quad = lane >> 4;
    const int l16  = lane & 15;
    const int wf   = wave >> 2;  // f/d half (0/1)
    const int wm   = wave & 3;   // m quarter (0..3), 32 rows each
    const int s7   = l16 & 7;

    const short* w1h = w1x + (size_t)h * 4 * CH_SH;
    const short* w2h = w2x + (size_t)h * 4 * CH_SH;

    // ---- prologue: stage chunk 0 of both weights (8 x 1KB glds per wave)
    {
        const char* s1 = (const char*)w1h;
        const char* s2 = (const char*)w2h;
        char* d1 = (char*)&W1s[0][0];
        char* d2 = (char*)&W2s[0][0];
        #pragma unroll
        for (int i = 0; i < 4; ++i)
            GLDS16(s1 + wave * 4096 + i * 1024 + lane * 16, d1 + wave * 4096 + i * 1024);
        #pragma unroll
        for (int i = 0; i < 4; ++i)
            GLDS16(s2 + wave * 4096 + i * 1024 + lane * 16, d2 + wave * 4096 + i * 1024);
    }

    // X as GEMM1 B-operand, kept bf16 in regs (32 VGPR); overlaps staging
    short8 xf[2][4];  // [mi][kk]
    {
        const float* xb = x + (size_t)(m0 + wm * 32) * DMODEL + h * DHEAD;
        #pragma unroll
        for (int mi = 0; mi < 2; ++mi)
            #pragma unroll
            for (int kk = 0; kk < 4; ++kk) {
                const float* p = xb + (size_t)(mi * 16 + l16) * DMODEL + kk * 32 + quad * 8;
                f32x4 a = *(const f32x4*)(p);
                f32x4 b = *(const f32x4*)(p + 4);
                short8 v;
                v[0] = f2bf(a[0]); v[1] = f2bf(a[1]); v[2] = f2bf(a[2]); v[3] = f2bf(a[3]);
                v[4] = f2bf(b[0]); v[5] = f2bf(b[1]); v[6] = f2bf(b[2]); v[7] = f2bf(b[3]);
                xf[mi][kk] = v;
            }
    }

    // hoisted b2 (constant per block)
    f32x4 bb2[4];
    #pragma unroll
    for (int di = 0; di < 4; ++di)
        bb2[di] = *(const f32x4*)(b2 + h * DHEAD + wf * 64 + di * 16 + quad * 4);

    f32x4 acc2[4][2];  // [di][mi], persistent across chunks
    #pragma unroll
    for (int di = 0; di < 4; ++di)
        #pragma unroll
        for (int mi = 0; mi < 2; ++mi)
            acc2[di][mi] = (f32x4){0.f, 0.f, 0.f, 0.f};

    const int arow = wf * 64 + l16;   // weight A-frag row base (+fi/di*16)

    // one-time drain: chunk-0 stages + xf + bb2 landed
    asm volatile("s_waitcnt vmcnt(0)" ::: "memory");
    __builtin_amdgcn_s_barrier();

    #pragma unroll
    for (int c = 0; c < 4; ++c) {
        const int buf = c & 1;
        // step 1: chunk-c buffers ready (prefetch glds are the ONLY
        // outstanding vmem here; issued a full GEMM2 ago). Barrier also
        // guarantees all waves are past chunk c-1 (Hs + buf^1 free).
        if (c) {
            asm volatile("s_waitcnt vmcnt(0)" ::: "memory");
            __builtin_amdgcn_s_barrier();
        }

        // b1 for this chunk (register loads, consumed after GEMM1)
        f32x4 bb1[4];
        #pragma unroll
        for (int fi = 0; fi < 4; ++fi)
            bb1[fi] = *(const f32x4*)(b1 + h * NFF + c * FC + wf * 64 + fi * 16 + quad * 4);

        // step 2: GEMM1 from W1s[buf] + xf regs
        f32x4 acc1[4][2];
        #pragma unroll
        for (int fi = 0; fi < 4; ++fi)
            #pragma unroll
            for (int mi = 0; mi < 2; ++mi)
                acc1[fi][mi] = (f32x4){0.f, 0.f, 0.f, 0.f};
        #pragma unroll
        for (int kk = 0; kk < 4; ++kk) {
            short8 af[4];
            #pragma unroll
            for (int fi = 0; fi < 4; ++fi)
                af[fi] = *(const short8*)&W1s[buf][(size_t)(arow + fi * 16) * 128 +
                                                  ((((kk << 2) + quad) ^ s7) << 3)];
            #pragma unroll
            for (int fi = 0; fi < 4; ++fi)
                #pragma unroll
                for (int mi = 0; mi < 2; ++mi)
                    acc1[fi][mi] = __builtin_amdgcn_mfma_f32_16x16x32_bf16(
                        af[fi], xf[mi][kk], acc1[fi][mi], 0, 0, 0);
        }

        // step 3: bias + relu -> Hs (swizzled 8B writes); overwrite of Hs is
        // safe: step-1 barrier put all waves past chunk c-1's GEMM2 reads.
        #pragma unroll
        for (int fi = 0; fi < 4; ++fi) {
            #pragma unroll
            for (int mi = 0; mi < 2; ++mi) {
                int mr = wm * 32 + mi * 16 + l16;
                short4v hv;
                #pragma unroll
                for (int r = 0; r < 4; ++r)
                    hv[r] = f2bf(fmaxf(acc1[fi][mi][r] + bb1[fi][r], 0.f));
                int g = (wf * 8 + fi * 2 + (quad >> 1)) ^ s7;
                *(short4v*)&Hs[(size_t)mr * 128 + g * 8 + (quad & 1) * 4] = hv;
            }
        }
        asm volatile("s_waitcnt lgkmcnt(0)" ::: "memory");
        __builtin_amdgcn_s_barrier();

        // step 4: issue chunk c+1 stages into buf^1 (safe: step-1 barrier
        // ensured chunk c-1's readers of buf^1 are all done). Consumed at
        // next chunk's step-1 wait => cover = GEMM2 below.
        if (c < 3) {
            const char* s1 = (const char*)(w1h + (size_t)(c + 1) * CH_SH);
            const char* s2 = (const char*)(w2h + (size_t)(c + 1) * CH_SH);
            char* d1 = (char*)&W1s[buf ^ 1][0];
            char* d2 = (char*)&W2s[buf ^ 1][0];
            #pragma unroll
            for (int i = 0; i < 4; ++i)
                GLDS16(s1 + wave * 4096 + i * 1024 + lane * 16, d1 + wave * 4096 + i * 1024);
            #pragma unroll
            for (int i = 0; i < 4; ++i)
                GLDS16(s2 + wave * 4096 + i * 1024 + lane * 16, d2 + wave * 4096 + i * 1024);
        }

        // step 5: GEMM2 from W2s[buf] + Hs
        #pragma unroll
        for (int kk = 0; kk < 4; ++kk) {
            short8 wfr[4], hfr[2];
            #pragma unroll
            for (int di = 0; di < 4; ++di)
                wfr[di] = *(const short8*)&W2s[buf][(size_t)(arow + di * 16) * 128 +
                                                   ((((kk << 2) + quad) ^ s7) << 3)];
            #pragma unroll
            for (int mi = 0; mi < 2; ++mi)
                hfr[mi] = *(const short8*)&Hs[(size_t)(wm * 32 + mi * 16 + l16) * 128 +
                                             ((((kk << 2) + quad) ^ s7) << 3)];
            #pragma unroll
            for (int di = 0; di < 4; ++di)
                #pragma unroll
                for (int mi = 0; mi < 2; ++mi)
                    acc2[di][mi] = __builtin_amdgcn_mfma_f32_16x16x32_bf16(
                        wfr[di], hfr[mi], acc2[di][mi], 0, 0, 0);
        }
    }

    // ---- epilogue: out[m][h*128+d] fp32, 16B stores
    #pragma unroll
    for (int di = 0; di < 4; ++di) {
        #pragma unroll
        for (int mi = 0; mi < 2; ++mi) {
            int m = m0 + wm * 32 + mi * 16 + l16;
            f32x4 ov;
            #pragma unroll
            for (int r = 0; r < 4; ++r)
                ov[r] = acc2[di][mi][r] + bb2[di][r];
            *(f32x4*)(out + (size_t)m * DMODEL + h * DHEAD + wf * 64 + di * 16 + quad * 4) = ov;
        }
    }
}

extern "C" void kernel_launch(void* const* d_in, const int* in_sizes, int n_in,
                              void* d_out, int out_size, void* d_ws, size_t ws_size,
                              hipStream_t stream) {
    const float* x  = (const float*)d_in[0];
    const float* W1 = (const float*)d_in[1];
    const float* b1 = (const float*)d_in[2];
    const float* W2 = (const float*)d_in[3];
    const float* b2 = (const float*)d_in[4];
    float* out = (float*)d_out;

    short* w1x = (short*)d_ws;                                     // [16][4][CH_SH]
    short* w2x = (short*)d_ws + (size_t)NHEADS * 4 * CH_SH;        // [16][4][CH_SH]

    transpose_both<<<dim3(16, 1, 2 * NHEADS), 256, 0, stream>>>(W1, W2, w1x, w2x);
    ffn_main<<<dim3(NTOK / MT * NHEADS), 512, 0, stream>>>(x, w1x, b1, w2x, b2, out);
}